// Round 1
// baseline (534.658 us; speedup 1.0000x reference)
//
#include <hip/hip_runtime.h>
#include <hip/hip_bf16.h>

// Problem constants
#define B_  8
#define D_  128
#define K_  7
#define Q_  256
#define G0_ 511
#define G0P 512   // padded K for the big GEMM
#define G1_ 512
#define F1_ 512
#define F2_ 1024
#define OUT_ 16

typedef __bf16 bf16x8 __attribute__((ext_vector_type(8)));
typedef float  f32x4  __attribute__((ext_vector_type(4)));

// ---------------------------------------------------------------------------
// K1a: u[b,i,g] = x[b,i,:] @ g0_w[0:7, g] + g0_b[g]   (pad g=511 -> 0)
//      v[b,i,g] = x[b,i,:] @ g0_w[7:14, g]            (pad g=511 -> 0)
// grid = B*D blocks, 512 threads
__global__ void k_uv(const float* __restrict__ x, const float* __restrict__ g0w,
                     const float* __restrict__ g0b, float* __restrict__ u,
                     float* __restrict__ v) {
    const int row = blockIdx.x;       // b*128 + i
    const int g   = threadIdx.x;      // 0..511
    __shared__ float xs[K_];
    if (threadIdx.x < K_) xs[threadIdx.x] = x[row * K_ + threadIdx.x];
    __syncthreads();
    float su = 0.f, sv = 0.f;
    if (g < G0_) {
        #pragma unroll
        for (int k = 0; k < K_; ++k) {
            su += xs[k] * g0w[k * G0_ + g];
            sv += xs[k] * g0w[(K_ + k) * G0_ + g];
        }
        su += g0b[g];
    }
    u[row * G0P + g] = (g < G0_) ? su : 0.f;
    v[row * G0P + g] = (g < G0_) ? sv : 0.f;
}

// ---------------------------------------------------------------------------
// K1b: W1bf[n][k] = bf16(g1_w[k][n]) for k<511, else 0.  (transposed, n-major)
// grid = 256 blocks (16x16 tiles of 32x32), 256 threads
__global__ void k_w1(const float* __restrict__ g1w, __bf16* __restrict__ w1bf) {
    __shared__ __bf16 tile[32][33];
    const int bx = blockIdx.x & 15;   // n tile
    const int by = blockIdx.x >> 4;   // k tile
    const int r  = threadIdx.x >> 5;  // 0..7
    const int c  = threadIdx.x & 31;
    #pragma unroll
    for (int i = 0; i < 4; ++i) {
        int k = by * 32 + r + i * 8;
        int n = bx * 32 + c;
        float vv = (k < G0_) ? g1w[k * G1_ + n] : 0.f;
        tile[r + i * 8][c] = (__bf16)vv;
    }
    __syncthreads();
    #pragma unroll
    for (int i = 0; i < 4; ++i) {
        int n = bx * 32 + r + i * 8;
        int k = by * 32 + c;
        w1bf[n * G0P + k] = tile[c][r + i * 8];
    }
}

// ---------------------------------------------------------------------------
// K1c: qterm[b][n] = g1_b[n] + qst[b,:] @ g1_w[511:767, n]
// grid = 8 blocks, 512 threads
__global__ void k_qterm(const float* __restrict__ qst, const float* __restrict__ g1w,
                        const float* __restrict__ g1b, float* __restrict__ qterm) {
    const int b = blockIdx.x;
    const int n = threadIdx.x;
    __shared__ float qs[Q_];
    if (n < Q_) qs[n] = qst[b * Q_ + n];
    __syncthreads();
    float a = g1b[n];
    #pragma unroll 8
    for (int q = 0; q < Q_; ++q)
        a += qs[q] * g1w[(G0_ + q) * G1_ + n];
    qterm[b * G1_ + n] = a;
}

// ---------------------------------------------------------------------------
// K2: the big fused GEMM.
// For each batch b, pair m=(a*128+c): A[m][k] = relu(u[b,c,k] + v[b,a,k]) (bias in u)
// C[m][n] = A[m][:] @ W1bf[n][:] ; then xg[b][n] += relu(C[m][n] + qterm[b][n])
// grid = B * 256 blocks (64 pairs each), 256 threads (4 waves, each 128 n's)
__global__ __launch_bounds__(256, 2)
void k_pair(const float* __restrict__ u, const float* __restrict__ v,
            const __bf16* __restrict__ w1bf, const float* __restrict__ qterm,
            float* __restrict__ xg) {
    const int bid  = blockIdx.x;
    const int b    = bid >> 8;        // batch
    const int mblk = bid & 255;       // 256 m-blocks of 64 pairs
    const int pair_base = mblk * 64;
    const int tid  = threadIdx.x;
    const int wave = tid >> 6;
    const int lane = tid & 63;
    const int quad = lane >> 4;
    const int l15  = lane & 15;
    const int nwave = wave * 128;

    f32x4 acc[4][8];
    #pragma unroll
    for (int mt = 0; mt < 4; ++mt)
        #pragma unroll
        for (int nt = 0; nt < 8; ++nt)
            acc[mt][nt] = (f32x4){0.f, 0.f, 0.f, 0.f};

    const bf16x8* wv = (const bf16x8*)w1bf;

    for (int kq = 0; kq < 16; ++kq) {
        const int kbase = kq * 32 + quad * 8;
        // B fragments: b_frag[j] = W1[k=kbase+j][n] = w1bf[n*512 + kbase + j]
        bf16x8 bfrag[8];
        #pragma unroll
        for (int nt = 0; nt < 8; ++nt) {
            int n = nwave + nt * 16 + l15;
            bfrag[nt] = wv[(n * G0P + kbase) >> 3];
        }
        #pragma unroll
        for (int mt = 0; mt < 4; ++mt) {
            const int pair = pair_base + mt * 16 + l15;
            const int a = pair >> 7;
            const int c = pair & 127;
            const float4 u0 = *(const float4*)(u + ((b * D_ + c) * G0P + kbase));
            const float4 u1 = *(const float4*)(u + ((b * D_ + c) * G0P + kbase + 4));
            const float4 v0 = *(const float4*)(v + ((b * D_ + a) * G0P + kbase));
            const float4 v1 = *(const float4*)(v + ((b * D_ + a) * G0P + kbase + 4));
            bf16x8 afrag;
            afrag[0] = (__bf16)fmaxf(u0.x + v0.x, 0.f);
            afrag[1] = (__bf16)fmaxf(u0.y + v0.y, 0.f);
            afrag[2] = (__bf16)fmaxf(u0.z + v0.z, 0.f);
            afrag[3] = (__bf16)fmaxf(u0.w + v0.w, 0.f);
            afrag[4] = (__bf16)fmaxf(u1.x + v1.x, 0.f);
            afrag[5] = (__bf16)fmaxf(u1.y + v1.y, 0.f);
            afrag[6] = (__bf16)fmaxf(u1.z + v1.z, 0.f);
            afrag[7] = (__bf16)fmaxf(u1.w + v1.w, 0.f);
            #pragma unroll
            for (int nt = 0; nt < 8; ++nt)
                acc[mt][nt] = __builtin_amdgcn_mfma_f32_16x16x32_bf16(
                    afrag, bfrag[nt], acc[mt][nt], 0, 0, 0);
        }
    }

    // Epilogue: relu(C + qterm), reduce over the 64 pair-rows, atomicAdd to xg.
    // C/D layout: col(n) = lane&15, row = quad*4 + reg.
    #pragma unroll
    for (int nt = 0; nt < 8; ++nt) {
        const int n = nwave + nt * 16 + l15;
        const float q = qterm[b * G1_ + n];
        float s = 0.f;
        #pragma unroll
        for (int mt = 0; mt < 4; ++mt)
            #pragma unroll
            for (int r = 0; r < 4; ++r)
                s += fmaxf(acc[mt][nt][r] + q, 0.f);
        s += __shfl_xor(s, 16, 64);
        s += __shfl_xor(s, 32, 64);
        if (quad == 0) atomicAdd(&xg[b * G1_ + n], s);
    }
}

// ---------------------------------------------------------------------------
// K3: f-MLP + log_softmax. grid = 8 blocks (one per batch), 256 threads.
__global__ void k_mlp(const float* __restrict__ xg,
                      const float* __restrict__ f1w, const float* __restrict__ f1b,
                      const float* __restrict__ f2w, const float* __restrict__ f2b,
                      const float* __restrict__ f3w, const float* __restrict__ f3b,
                      float* __restrict__ out) {
    const int b = blockIdx.x;
    const int t = threadIdx.x;
    __shared__ float xs[F1_];
    __shared__ float s1[F1_];
    __shared__ float s2[F2_];
    __shared__ float lg[OUT_];
    xs[t]       = xg[b * G1_ + t];
    xs[t + 256] = xg[b * G1_ + t + 256];
    __syncthreads();
    #pragma unroll
    for (int i = 0; i < 2; ++i) {
        const int o = t + i * 256;
        float a = f1b[o];
        #pragma unroll 8
        for (int k = 0; k < G1_; ++k) a += xs[k] * f1w[k * F1_ + o];
        s1[o] = fmaxf(a, 0.f);
    }
    __syncthreads();
    #pragma unroll
    for (int i = 0; i < 4; ++i) {
        const int o = t + i * 256;
        float a = f2b[o];
        #pragma unroll 8
        for (int k = 0; k < F1_; ++k) a += s1[k] * f2w[k * F2_ + o];
        s2[o] = fmaxf(a, 0.f);
    }
    __syncthreads();
    if (t < OUT_) {
        float a = f3b[t];
        #pragma unroll 8
        for (int k = 0; k < F2_; ++k) a += s2[k] * f3w[k * OUT_ + t];
        lg[t] = a;
    }
    __syncthreads();
    if (t < OUT_) {
        float m = -1e30f;
        #pragma unroll
        for (int i = 0; i < OUT_; ++i) m = fmaxf(m, lg[i]);
        float se = 0.f;
        #pragma unroll
        for (int i = 0; i < OUT_; ++i) se += __expf(lg[i] - m);
        out[b * OUT_ + t] = lg[t] - m - logf(se);
    }
}

// ---------------------------------------------------------------------------
extern "C" void kernel_launch(void* const* d_in, const int* in_sizes, int n_in,
                              void* d_out, int out_size, void* d_ws, size_t ws_size,
                              hipStream_t stream) {
    const float* x   = (const float*)d_in[0];
    const float* qst = (const float*)d_in[1];
    const float* g0w = (const float*)d_in[2];
    const float* g0b = (const float*)d_in[3];
    const float* g1w = (const float*)d_in[4];
    const float* g1b = (const float*)d_in[5];
    const float* f1w = (const float*)d_in[6];
    const float* f1b = (const float*)d_in[7];
    const float* f2w = (const float*)d_in[8];
    const float* f2b = (const float*)d_in[9];
    const float* f3w = (const float*)d_in[10];
    const float* f3b = (const float*)d_in[11];

    char* ws = (char*)d_ws;
    float*  u     = (float*)ws;  ws += (size_t)B_ * D_ * G0P * 4;   // 2 MB
    float*  v     = (float*)ws;  ws += (size_t)B_ * D_ * G0P * 4;   // 2 MB
    __bf16* w1bf  = (__bf16*)ws; ws += (size_t)G1_ * G0P * 2;       // 512 KB
    float*  qterm = (float*)ws;  ws += (size_t)B_ * G1_ * 4;        // 16 KB
    float*  xg    = (float*)ws;  ws += (size_t)B_ * G1_ * 4;        // 16 KB

    hipMemsetAsync(xg, 0, (size_t)B_ * G1_ * 4, stream);

    k_uv   <<<B_ * D_, 512, 0, stream>>>(x, g0w, g0b, u, v);
    k_w1   <<<256, 256, 0, stream>>>(g1w, w1bf);
    k_qterm<<<B_, G1_, 0, stream>>>(qst, g1w, g1b, qterm);
    k_pair <<<B_ * 256, 256, 0, stream>>>(u, v, w1bf, qterm, xg);
    k_mlp  <<<B_, 256, 0, stream>>>(xg, f1w, f1b, f2w, f2b, f3w, f3b, (float*)d_out);
}

// Round 2
// 270.594 us; speedup vs baseline: 1.9759x; 1.9759x over previous
//
#include <hip/hip_runtime.h>
#include <hip/hip_bf16.h>

#define B_  8
#define D_  128
#define K_  7
#define Q_  256
#define G0_ 511
#define G0P 512
#define G1_ 512
#define F1_ 512
#define F2_ 1024
#define OUT_ 16

typedef __bf16 bf16x8 __attribute__((ext_vector_type(8)));
typedef float  f32x4  __attribute__((ext_vector_type(4)));

// ---------------------------------------------------------------------------
// k_prep: fused preprocessing, 1320 blocks x 256 threads.
//  [0,1024):    u/v rows        (one (b,i) row per block)
//  [1024,1280): w1 bf16 transpose
//  [1280,1312): qterm
//  [1312,1320): zero xg
__global__ void k_prep(const float* __restrict__ x, const float* __restrict__ g0w,
                       const float* __restrict__ g0b, const float* __restrict__ qst,
                       const float* __restrict__ g1w, const float* __restrict__ g1b,
                       float* __restrict__ u, float* __restrict__ v,
                       __bf16* __restrict__ w1bf, float* __restrict__ qterm,
                       float* __restrict__ xg) {
    const int blk = blockIdx.x;
    const int t   = threadIdx.x;
    if (blk < 1024) {
        __shared__ float xs[8];
        if (t < K_) xs[t] = x[blk * K_ + t];
        __syncthreads();
        #pragma unroll
        for (int h = 0; h < 2; ++h) {
            const int g = t + h * 256;
            float su = 0.f, sv = 0.f;
            if (g < G0_) {
                #pragma unroll
                for (int k = 0; k < K_; ++k) {
                    su += xs[k] * g0w[k * G0_ + g];
                    sv += xs[k] * g0w[(K_ + k) * G0_ + g];
                }
                su += g0b[g];
            }
            u[blk * G0P + g] = (g < G0_) ? su : 0.f;
            v[blk * G0P + g] = (g < G0_) ? sv : 0.f;
        }
    } else if (blk < 1280) {
        __shared__ __bf16 tile[32][33];
        const int bb = blk - 1024;
        const int bx = bb & 15, by = bb >> 4;
        const int r = t >> 5, c = t & 31;
        #pragma unroll
        for (int i = 0; i < 4; ++i) {
            const int k = by * 32 + r + i * 8;
            const int n = bx * 32 + c;
            tile[r + i * 8][c] = (__bf16)((k < G0_) ? g1w[k * G1_ + n] : 0.f);
        }
        __syncthreads();
        #pragma unroll
        for (int i = 0; i < 4; ++i)
            w1bf[(bx * 32 + r + i * 8) * G0P + by * 32 + c] = tile[c][r + i * 8];
    } else if (blk < 1312) {
        __shared__ float qs[256];
        __shared__ float red[2][128];
        const int qb = blk - 1280;
        const int b = qb >> 2, nb = (qb & 3) << 7;
        qs[t] = qst[b * Q_ + t];
        __syncthreads();
        const int n = nb + (t & 127);
        const int qh = (t >> 7) * 128;
        float s = 0.f;
        #pragma unroll 8
        for (int q = 0; q < 128; ++q)
            s += qs[qh + q] * g1w[(G0_ + qh + q) * G1_ + n];
        red[t >> 7][t & 127] = s;
        __syncthreads();
        if (t < 128)
            qterm[b * G1_ + nb + t] = red[0][t] + red[1][t] + g1b[nb + t];
    } else {
        const int b = blk - 1312;
        xg[b * G1_ + t] = 0.f;
        xg[b * G1_ + 256 + t] = 0.f;
    }
}

// ---------------------------------------------------------------------------
// k_pair: block = (b, a, nhalf). M=128 (all c), N=256. A = relu(u[c]+v_a)
// staged in LDS in MFMA-fragment order (conflict-free ds_read_b128),
// double-buffered; u loads for kq+1 issued before the MFMA block.
__global__ __launch_bounds__(256, 2)
void k_pair(const float* __restrict__ u, const float* __restrict__ v,
            const __bf16* __restrict__ w1bf, const float* __restrict__ qterm,
            float* __restrict__ xg) {
    __shared__ float  v_a[512];
    __shared__ __bf16 At[2][4096];     // [buf][mtile(8)][lane(64)*8]
    __shared__ float  ebuf[4][128];

    const int bid  = blockIdx.x;
    const int b    = bid >> 8;
    const int a    = (bid >> 1) & 127;
    const int nbase = (bid & 1) << 8;
    const int tid  = threadIdx.x;
    const int wave = tid >> 6, lane = tid & 63;
    const int quad = lane >> 4, l15 = lane & 15;
    const int ncol = nbase + (wave >> 1) * 128;
    const int mtg_base = (wave & 1) * 4;

    if (tid < 128)
        *(float4*)(v_a + tid * 4) = *(const float4*)(v + (b * D_ + a) * G0P + tid * 4);

    // staging geometry: thread -> (m = tid>>1, k-off = (tid&1)*16)
    const int sm = tid >> 1;
    const int sk = (tid & 1) << 4;
    const float* urow = u + (b * D_ + sm) * G0P + sk;
    const int woff = (sm >> 4) * 512 + (sk >> 3) * 128 + (sm & 15) * 8;

    f32x4 acc[4][8];
    #pragma unroll
    for (int mt = 0; mt < 4; ++mt)
        #pragma unroll
        for (int nt = 0; nt < 8; ++nt)
            acc[mt][nt] = (f32x4){0.f, 0.f, 0.f, 0.f};

    __syncthreads();   // v_a visible

    float4 u0, u1, u2, u3;
    auto load_u = [&](int kq) {
        const float* p = urow + kq * 32;
        u0 = *(const float4*)p;       u1 = *(const float4*)(p + 4);
        u2 = *(const float4*)(p + 8); u3 = *(const float4*)(p + 12);
    };
    auto write_A = [&](int buf, int kq) {
        const float* vp = v_a + kq * 32 + sk;
        const float4 v0 = *(const float4*)vp,       v1 = *(const float4*)(vp + 4);
        const float4 v2 = *(const float4*)(vp + 8), v3 = *(const float4*)(vp + 12);
        bf16x8 h0, h1;
        h0[0] = (__bf16)fmaxf(u0.x + v0.x, 0.f);
        h0[1] = (__bf16)fmaxf(u0.y + v0.y, 0.f);
        h0[2] = (__bf16)fmaxf(u0.z + v0.z, 0.f);
        h0[3] = (__bf16)fmaxf(u0.w + v0.w, 0.f);
        h0[4] = (__bf16)fmaxf(u1.x + v1.x, 0.f);
        h0[5] = (__bf16)fmaxf(u1.y + v1.y, 0.f);
        h0[6] = (__bf16)fmaxf(u1.z + v1.z, 0.f);
        h0[7] = (__bf16)fmaxf(u1.w + v1.w, 0.f);
        h1[0] = (__bf16)fmaxf(u2.x + v2.x, 0.f);
        h1[1] = (__bf16)fmaxf(u2.y + v2.y, 0.f);
        h1[2] = (__bf16)fmaxf(u2.z + v2.z, 0.f);
        h1[3] = (__bf16)fmaxf(u2.w + v2.w, 0.f);
        h1[4] = (__bf16)fmaxf(u3.x + v3.x, 0.f);
        h1[5] = (__bf16)fmaxf(u3.y + v3.y, 0.f);
        h1[6] = (__bf16)fmaxf(u3.z + v3.z, 0.f);
        h1[7] = (__bf16)fmaxf(u3.w + v3.w, 0.f);
        __bf16* w = &At[buf][woff];
        *(bf16x8*)w = h0;
        *(bf16x8*)(w + 128) = h1;
    };

    load_u(0);
    write_A(0, 0);
    __syncthreads();

    const bf16x8* wv = (const bf16x8*)w1bf;
    for (int kq = 0; kq < 16; ++kq) {
        const int buf = kq & 1;
        if (kq < 15) load_u(kq + 1);               // prefetch next u slice
        bf16x8 af[4];
        #pragma unroll
        for (int mt = 0; mt < 4; ++mt)
            af[mt] = *(const bf16x8*)&At[buf][(mtg_base + mt) * 512 + lane * 8];
        bf16x8 bfr[8];
        #pragma unroll
        for (int nt = 0; nt < 8; ++nt)
            bfr[nt] = wv[(ncol + nt * 16 + l15) * 64 + kq * 4 + quad];
        #pragma unroll
        for (int mt = 0; mt < 4; ++mt)
            #pragma unroll
            for (int nt = 0; nt < 8; ++nt)
                acc[mt][nt] = __builtin_amdgcn_mfma_f32_16x16x32_bf16(
                    af[mt], bfr[nt], acc[mt][nt], 0, 0, 0);
        if (kq < 15) write_A(buf ^ 1, kq + 1);     // store next A tile
        __syncthreads();
    }

    // epilogue: relu(C + qterm), reduce over 64 m-rows per wave, combine, atomic
    #pragma unroll
    for (int nt = 0; nt < 8; ++nt) {
        const float q = qterm[b * G1_ + ncol + nt * 16 + l15];
        float s = 0.f;
        #pragma unroll
        for (int mt = 0; mt < 4; ++mt)
            #pragma unroll
            for (int r = 0; r < 4; ++r)
                s += fmaxf(acc[mt][nt][r] + q, 0.f);
        s += __shfl_xor(s, 16, 64);
        s += __shfl_xor(s, 32, 64);
        if (quad == 0) ebuf[wave][nt * 16 + l15] = s;
    }
    __syncthreads();
    {
        const int grp = tid >> 7, nl = tid & 127;
        const float sv = ebuf[grp * 2][nl] + ebuf[grp * 2 + 1][nl];
        atomicAdd(xg + b * G1_ + nbase + grp * 128 + nl, sv);
    }
}

// ---------------------------------------------------------------------------
// f-MLP, parallelized: k_f1 (64 blocks), k_f2 (128 blocks), k_f3+softmax (8).
__global__ void k_f1(const float* __restrict__ xg, const float* __restrict__ f1w,
                     const float* __restrict__ f1b, float* __restrict__ s1g) {
    const int b = blockIdx.x >> 3, ob = (blockIdx.x & 7) << 6;
    const int t = threadIdx.x;
    __shared__ float xs[512];
    __shared__ float red[4][64];
    xs[t] = xg[b * G1_ + t];
    xs[t + 256] = xg[b * G1_ + 256 + t];
    __syncthreads();
    const int o = ob + (t & 63), kq = t >> 6;
    float s = 0.f;
    #pragma unroll 8
    for (int j = 0; j < 128; ++j)
        s += xs[kq * 128 + j] * f1w[(kq * 128 + j) * F1_ + o];
    red[kq][t & 63] = s;
    __syncthreads();
    if (t < 64)
        s1g[b * F1_ + ob + t] =
            fmaxf(red[0][t] + red[1][t] + red[2][t] + red[3][t] + f1b[ob + t], 0.f);
}

__global__ void k_f2(const float* __restrict__ s1g, const float* __restrict__ f2w,
                     const float* __restrict__ f2b, float* __restrict__ s2g) {
    const int b = blockIdx.x >> 4, ob = (blockIdx.x & 15) << 6;
    const int t = threadIdx.x;
    __shared__ float xs[512];
    __shared__ float red[4][64];
    xs[t] = s1g[b * F1_ + t];
    xs[t + 256] = s1g[b * F1_ + 256 + t];
    __syncthreads();
    const int o = ob + (t & 63), kq = t >> 6;
    float s = 0.f;
    #pragma unroll 8
    for (int j = 0; j < 128; ++j)
        s += xs[kq * 128 + j] * f2w[(kq * 128 + j) * F2_ + o];
    red[kq][t & 63] = s;
    __syncthreads();
    if (t < 64)
        s2g[b * F2_ + ob + t] =
            fmaxf(red[0][t] + red[1][t] + red[2][t] + red[3][t] + f2b[ob + t], 0.f);
}

__global__ void k_f3(const float* __restrict__ s2g, const float* __restrict__ f3w,
                     const float* __restrict__ f3b, float* __restrict__ out) {
    const int b = blockIdx.x, t = threadIdx.x;
    __shared__ float xs[1024];
    __shared__ float red[16][16];
    __shared__ float lg[16];
    #pragma unroll
    for (int i = 0; i < 4; ++i) xs[t + i * 256] = s2g[b * F2_ + t + i * 256];
    __syncthreads();
    const int o = t & 15, kq = t >> 4;
    float s = 0.f;
    #pragma unroll 8
    for (int j = 0; j < 64; ++j)
        s += xs[kq * 64 + j] * f3w[(kq * 64 + j) * OUT_ + o];
    red[kq][o] = s;
    __syncthreads();
    if (t < 16) {
        float a = f3b[t];
        #pragma unroll
        for (int i = 0; i < 16; ++i) a += red[i][t];
        lg[t] = a;
    }
    __syncthreads();
    if (t < 16) {
        float m = -1e30f;
        #pragma unroll
        for (int i = 0; i < 16; ++i) m = fmaxf(m, lg[i]);
        float se = 0.f;
        #pragma unroll
        for (int i = 0; i < 16; ++i) se += __expf(lg[i] - m);
        out[b * OUT_ + t] = lg[t] - m - logf(se);
    }
}

// ---------------------------------------------------------------------------
extern "C" void kernel_launch(void* const* d_in, const int* in_sizes, int n_in,
                              void* d_out, int out_size, void* d_ws, size_t ws_size,
                              hipStream_t stream) {
    const float* x   = (const float*)d_in[0];
    const float* qst = (const float*)d_in[1];
    const float* g0w = (const float*)d_in[2];
    const float* g0b = (const float*)d_in[3];
    const float* g1w = (const float*)d_in[4];
    const float* g1b = (const float*)d_in[5];
    const float* f1w = (const float*)d_in[6];
    const float* f1b = (const float*)d_in[7];
    const float* f2w = (const float*)d_in[8];
    const float* f2b = (const float*)d_in[9];
    const float* f3w = (const float*)d_in[10];
    const float* f3b = (const float*)d_in[11];

    char* ws = (char*)d_ws;
    float*  u     = (float*)ws;  ws += (size_t)B_ * D_ * G0P * 4;
    float*  v     = (float*)ws;  ws += (size_t)B_ * D_ * G0P * 4;
    __bf16* w1bf  = (__bf16*)ws; ws += (size_t)G1_ * G0P * 2;
    float*  qterm = (float*)ws;  ws += (size_t)B_ * G1_ * 4;
    float*  xg    = (float*)ws;  ws += (size_t)B_ * G1_ * 4;
    float*  s1g   = (float*)ws;  ws += (size_t)B_ * F1_ * 4;
    float*  s2g   = (float*)ws;  ws += (size_t)B_ * F2_ * 4;

    k_prep<<<1320, 256, 0, stream>>>(x, g0w, g0b, qst, g1w, g1b,
                                     u, v, w1bf, qterm, xg);
    k_pair<<<B_ * D_ * 2, 256, 0, stream>>>(u, v, w1bf, qterm, xg);
    k_f1  <<<64, 256, 0, stream>>>(xg, f1w, f1b, s1g);
    k_f2  <<<128, 256, 0, stream>>>(s1g, f2w, f2b, s2g);
    k_f3  <<<B_, 256, 0, stream>>>(s2g, f3w, f3b, (float*)d_out);
}

// Round 3
// 202.648 us; speedup vs baseline: 2.6384x; 1.3353x over previous
//
#include <hip/hip_runtime.h>
#include <hip/hip_bf16.h>

#define B_  8
#define D_  128
#define K_  7
#define Q_  256
#define G0_ 511
#define G0P 512
#define G1_ 512
#define F1_ 512
#define F2_ 1024
#define OUT_ 16

typedef __bf16 bf16x8 __attribute__((ext_vector_type(8)));
typedef float  f32x4  __attribute__((ext_vector_type(4)));

// async global->LDS, 16B per lane; LDS dest = wave-uniform base + lane*16
#define GL2LDS(g, l) __builtin_amdgcn_global_load_lds(                        \
    (const __attribute__((address_space(1))) void*)(g),                       \
    (__attribute__((address_space(3))) void*)(l), 16, 0, 0)

// ---------------------------------------------------------------------------
// k_prep: fused preprocessing, 1320 blocks x 256 threads.
//  [0,1024):    u/v rows
//  [1024,1280): w1 -> pre-tiled swizzled bf16 w1t[kq][n][chunk^((n>>1)&3)]
//  [1280,1312): qterm
//  [1312,1320): zero xg
__global__ void k_prep(const float* __restrict__ x, const float* __restrict__ g0w,
                       const float* __restrict__ g0b, const float* __restrict__ qst,
                       const float* __restrict__ g1w, const float* __restrict__ g1b,
                       float* __restrict__ u, float* __restrict__ v,
                       __bf16* __restrict__ w1t, float* __restrict__ qterm,
                       float* __restrict__ xg) {
    const int blk = blockIdx.x;
    const int t   = threadIdx.x;
    if (blk < 1024) {
        __shared__ float xs[8];
        if (t < K_) xs[t] = x[blk * K_ + t];
        __syncthreads();
        #pragma unroll
        for (int h = 0; h < 2; ++h) {
            const int g = t + h * 256;
            float su = 0.f, sv = 0.f;
            if (g < G0_) {
                #pragma unroll
                for (int k = 0; k < K_; ++k) {
                    su += xs[k] * g0w[k * G0_ + g];
                    sv += xs[k] * g0w[(K_ + k) * G0_ + g];
                }
                su += g0b[g];
            }
            u[blk * G0P + g] = (g < G0_) ? su : 0.f;
            v[blk * G0P + g] = (g < G0_) ? sv : 0.f;
        }
    } else if (blk < 1280) {
        __shared__ __bf16 tile[32][33];
        const int bb = blk - 1024;
        const int bx = bb & 15, by = bb >> 4;   // by = kq tile (k = by*32+c)
        const int r = t >> 5, c = t & 31;
        #pragma unroll
        for (int i = 0; i < 4; ++i) {
            const int k = by * 32 + r + i * 8;
            const int n = bx * 32 + c;
            tile[r + i * 8][c] = (__bf16)((k < G0_) ? g1w[k * G1_ + n] : 0.f);
        }
        __syncthreads();
        #pragma unroll
        for (int i = 0; i < 4; ++i) {
            const int n = bx * 32 + r + i * 8;
            const int cc = (c >> 3) & 3, j = c & 7;
            const int slot = cc ^ ((n >> 1) & 3);
            w1t[by * 16384 + n * 32 + slot * 8 + j] = tile[c][r + i * 8];
        }
    } else if (blk < 1312) {
        __shared__ float qs[256];
        __shared__ float red[2][128];
        const int qb = blk - 1280;
        const int b = qb >> 2, nb = (qb & 3) << 7;
        qs[t] = qst[b * Q_ + t];
        __syncthreads();
        const int n = nb + (t & 127);
        const int qh = (t >> 7) * 128;
        float s = 0.f;
        #pragma unroll 8
        for (int q = 0; q < 128; ++q)
            s += qs[qh + q] * g1w[(G0_ + qh + q) * G1_ + n];
        red[t >> 7][t & 127] = s;
        __syncthreads();
        if (t < 128)
            qterm[b * G1_ + nb + t] = red[0][t] + red[1][t] + g1b[nb + t];
    } else {
        const int b = blk - 1312;
        xg[b * G1_ + t] = 0.f;
        xg[b * G1_ + 256 + t] = 0.f;
    }
}

// ---------------------------------------------------------------------------
// k_pair: block = (b, a, nhalf). M=128, N=256, K=512.
// A = relu(u[c]+v_a) staged in LDS (fragment order); B DMA'd via
// global_load_lds from pre-tiled swizzled w1t; both double-buffered.
__global__ __launch_bounds__(256, 2)
void k_pair(const float* __restrict__ u, const float* __restrict__ v,
            const __bf16* __restrict__ w1t, const float* __restrict__ qterm,
            float* __restrict__ xg) {
    __shared__ float  v_a[512];
    __shared__ __bf16 At[2][4096];     // [buf][mtile(8)][lane(64)*8]
    __shared__ __bf16 Bt[2][8192];     // [buf][n_local(256)][32k swizzled]
    __shared__ float  ebuf[4][128];

    const int bid  = blockIdx.x;
    const int b    = bid >> 8;
    const int a    = (bid >> 1) & 127;
    const int nbase = (bid & 1) << 8;
    const int tid  = threadIdx.x;
    const int wave = tid >> 6, lane = tid & 63;
    const int quad = lane >> 4, l15 = lane & 15;
    const int nloc = (wave >> 1) * 128;    // wave's n offset within [0,256)
    const int mtg  = (wave & 1) * 4;       // wave's mtile base
    const int swz  = (l15 >> 1) & 3;

    if (tid < 128)
        *(float4*)(v_a + tid * 4) = *(const float4*)(v + (b * D_ + a) * G0P + tid * 4);

    // B staging: wave issues 4 DMA instrs, instr j covers n_local [(wave*4+j)*16,+16)
    const int iw0 = wave * 4;
    const __bf16* gsrc = w1t + (size_t)(nbase + iw0 * 16 + (lane >> 2)) * 32
                             + (lane & 3) * 8;

    // A staging geometry: thread -> (m = tid>>1, k-off = (tid&1)*16)
    const int sm = tid >> 1;
    const int sk = (tid & 1) << 4;
    const float* urow = u + (b * D_ + sm) * G0P + sk;
    const int woff = (sm >> 4) * 512 + (sk >> 3) * 128 + (sm & 15) * 8;

    f32x4 acc[4][8];
    #pragma unroll
    for (int mt = 0; mt < 4; ++mt)
        #pragma unroll
        for (int nt = 0; nt < 8; ++nt)
            acc[mt][nt] = (f32x4){0.f, 0.f, 0.f, 0.f};

    float4 u0, u1, u2, u3;
    auto load_u = [&](int kq) {
        const float* p = urow + kq * 32;
        u0 = *(const float4*)p;       u1 = *(const float4*)(p + 4);
        u2 = *(const float4*)(p + 8); u3 = *(const float4*)(p + 12);
    };
    auto stage_B = [&](int buf, int kq) {
        const __bf16* g = gsrc + kq * 16384;
        __bf16* l = &Bt[buf][iw0 * 512];
        #pragma unroll
        for (int j = 0; j < 4; ++j)
            GL2LDS(g + j * 512, l + j * 512);
    };
    auto write_A = [&](int buf, int kq) {
        const float* vp = v_a + kq * 32 + sk;
        const float4 v0 = *(const float4*)vp,       v1 = *(const float4*)(vp + 4);
        const float4 v2 = *(const float4*)(vp + 8), v3 = *(const float4*)(vp + 12);
        bf16x8 h0, h1;
        h0[0] = (__bf16)fmaxf(u0.x + v0.x, 0.f);
        h0[1] = (__bf16)fmaxf(u0.y + v0.y, 0.f);
        h0[2] = (__bf16)fmaxf(u0.z + v0.z, 0.f);
        h0[3] = (__bf16)fmaxf(u0.w + v0.w, 0.f);
        h0[4] = (__bf16)fmaxf(u1.x + v1.x, 0.f);
        h0[5] = (__bf16)fmaxf(u1.y + v1.y, 0.f);
        h0[6] = (__bf16)fmaxf(u1.z + v1.z, 0.f);
        h0[7] = (__bf16)fmaxf(u1.w + v1.w, 0.f);
        h1[0] = (__bf16)fmaxf(u2.x + v2.x, 0.f);
        h1[1] = (__bf16)fmaxf(u2.y + v2.y, 0.f);
        h1[2] = (__bf16)fmaxf(u2.z + v2.z, 0.f);
        h1[3] = (__bf16)fmaxf(u2.w + v2.w, 0.f);
        h1[4] = (__bf16)fmaxf(u3.x + v3.x, 0.f);
        h1[5] = (__bf16)fmaxf(u3.y + v3.y, 0.f);
        h1[6] = (__bf16)fmaxf(u3.z + v3.z, 0.f);
        h1[7] = (__bf16)fmaxf(u3.w + v3.w, 0.f);
        __bf16* w = &At[buf][woff];
        *(bf16x8*)w = h0;
        *(bf16x8*)(w + 128) = h1;
    };

    // prologue
    stage_B(0, 0);
    load_u(0);
    __syncthreads();               // v_a visible, Bt[0] DMA drained
    write_A(0, 0);
    __syncthreads();               // At[0] visible

    for (int kq = 0; kq < 16; ++kq) {
        const int buf = kq & 1;
        if (kq < 15) {
            stage_B(buf ^ 1, kq + 1);      // async DMA into other buffer
            load_u(kq + 1);                // u regs for next A tile
        }
        bf16x8 af[4];
        #pragma unroll
        for (int mt = 0; mt < 4; ++mt)
            af[mt] = *(const bf16x8*)&At[buf][(mtg + mt) * 512 + lane * 8];
        bf16x8 bfr[8];
        const __bf16* btb = &Bt[buf][(nloc + l15) * 32 + ((quad ^ swz) << 3)];
        #pragma unroll
        for (int nt = 0; nt < 8; ++nt)
            bfr[nt] = *(const bf16x8*)(btb + nt * 512);
        #pragma unroll
        for (int mt = 0; mt < 4; ++mt)
            #pragma unroll
            for (int nt = 0; nt < 8; ++nt)
                acc[mt][nt] = __builtin_amdgcn_mfma_f32_16x16x32_bf16(
                    af[mt], bfr[nt], acc[mt][nt], 0, 0, 0);
        if (kq < 15) write_A(buf ^ 1, kq + 1);
        __syncthreads();           // drains DMA + ds_writes for buf^1
    }

    // epilogue: relu(C + qterm), reduce over 64 m-rows per wave, combine, atomic
    #pragma unroll
    for (int nt = 0; nt < 8; ++nt) {
        const float q = qterm[b * G1_ + nbase + nloc + nt * 16 + l15];
        float s = 0.f;
        #pragma unroll
        for (int mt = 0; mt < 4; ++mt)
            #pragma unroll
            for (int r = 0; r < 4; ++r)
                s += fmaxf(acc[mt][nt][r] + q, 0.f);
        s += __shfl_xor(s, 16, 64);
        s += __shfl_xor(s, 32, 64);
        if (quad == 0) ebuf[wave][nt * 16 + l15] = s;
    }
    __syncthreads();
    {
        const int grp = tid >> 7, nl = tid & 127;
        const float sv = ebuf[grp * 2][nl] + ebuf[grp * 2 + 1][nl];
        atomicAdd(xg + b * G1_ + nbase + grp * 128 + nl, sv);
    }
}

// ---------------------------------------------------------------------------
// f-MLP: k_f1 (64 blocks), k_f2 (128 blocks), k_f3+softmax (8 blocks).
__global__ void k_f1(const float* __restrict__ xg, const float* __restrict__ f1w,
                     const float* __restrict__ f1b, float* __restrict__ s1g) {
    const int b = blockIdx.x >> 3, ob = (blockIdx.x & 7) << 6;
    const int t = threadIdx.x;
    __shared__ float xs[512];
    __shared__ float red[4][64];
    xs[t] = xg[b * G1_ + t];
    xs[t + 256] = xg[b * G1_ + 256 + t];
    __syncthreads();
    const int o = ob + (t & 63), kq = t >> 6;
    float s = 0.f;
    #pragma unroll 8
    for (int j = 0; j < 128; ++j)
        s += xs[kq * 128 + j] * f1w[(kq * 128 + j) * F1_ + o];
    red[kq][t & 63] = s;
    __syncthreads();
    if (t < 64)
        s1g[b * F1_ + ob + t] =
            fmaxf(red[0][t] + red[1][t] + red[2][t] + red[3][t] + f1b[ob + t], 0.f);
}

__global__ void k_f2(const float* __restrict__ s1g, const float* __restrict__ f2w,
                     const float* __restrict__ f2b, float* __restrict__ s2g) {
    const int b = blockIdx.x >> 4, ob = (blockIdx.x & 15) << 6;
    const int t = threadIdx.x;
    __shared__ float xs[512];
    __shared__ float red[4][64];
    xs[t] = s1g[b * F1_ + t];
    xs[t + 256] = s1g[b * F1_ + 256 + t];
    __syncthreads();
    const int o = ob + (t & 63), kq = t >> 6;
    float s = 0.f;
    #pragma unroll 8
    for (int j = 0; j < 128; ++j)
        s += xs[kq * 128 + j] * f2w[(kq * 128 + j) * F2_ + o];
    red[kq][t & 63] = s;
    __syncthreads();
    if (t < 64)
        s2g[b * F2_ + ob + t] =
            fmaxf(red[0][t] + red[1][t] + red[2][t] + red[3][t] + f2b[ob + t], 0.f);
}

__global__ void k_f3(const float* __restrict__ s2g, const float* __restrict__ f3w,
                     const float* __restrict__ f3b, float* __restrict__ out) {
    const int b = blockIdx.x, t = threadIdx.x;
    __shared__ float xs[1024];
    __shared__ float red[16][16];
    __shared__ float lg[16];
    #pragma unroll
    for (int i = 0; i < 4; ++i) xs[t + i * 256] = s2g[b * F2_ + t + i * 256];
    __syncthreads();
    const int o = t & 15, kq = t >> 4;
    float s = 0.f;
    #pragma unroll 8
    for (int j = 0; j < 64; ++j)
        s += xs[kq * 64 + j] * f3w[(kq * 64 + j) * OUT_ + o];
    red[kq][o] = s;
    __syncthreads();
    if (t < 16) {
        float a = f3b[t];
        #pragma unroll
        for (int i = 0; i < 16; ++i) a += red[i][t];
        lg[t] = a;
    }
    __syncthreads();
    if (t < 16) {
        float m = -1e30f;
        #pragma unroll
        for (int i = 0; i < 16; ++i) m = fmaxf(m, lg[i]);
        float se = 0.f;
        #pragma unroll
        for (int i = 0; i < 16; ++i) se += __expf(lg[i] - m);
        out[b * OUT_ + t] = lg[t] - m - logf(se);
    }
}

// ---------------------------------------------------------------------------
extern "C" void kernel_launch(void* const* d_in, const int* in_sizes, int n_in,
                              void* d_out, int out_size, void* d_ws, size_t ws_size,
                              hipStream_t stream) {
    const float* x   = (const float*)d_in[0];
    const float* qst = (const float*)d_in[1];
    const float* g0w = (const float*)d_in[2];
    const float* g0b = (const float*)d_in[3];
    const float* g1w = (const float*)d_in[4];
    const float* g1b = (const float*)d_in[5];
    const float* f1w = (const float*)d_in[6];
    const float* f1b = (const float*)d_in[7];
    const float* f2w = (const float*)d_in[8];
    const float* f2b = (const float*)d_in[9];
    const float* f3w = (const float*)d_in[10];
    const float* f3b = (const float*)d_in[11];

    char* ws = (char*)d_ws;
    float*  u     = (float*)ws;  ws += (size_t)B_ * D_ * G0P * 4;
    float*  v     = (float*)ws;  ws += (size_t)B_ * D_ * G0P * 4;
    __bf16* w1t   = (__bf16*)ws; ws += (size_t)G1_ * G0P * 2;
    float*  qterm = (float*)ws;  ws += (size_t)B_ * G1_ * 4;
    float*  xg    = (float*)ws;  ws += (size_t)B_ * G1_ * 4;
    float*  s1g   = (float*)ws;  ws += (size_t)B_ * F1_ * 4;
    float*  s2g   = (float*)ws;  ws += (size_t)B_ * F2_ * 4;

    k_prep<<<1320, 256, 0, stream>>>(x, g0w, g0b, qst, g1w, g1b,
                                     u, v, w1t, qterm, xg);
    k_pair<<<B_ * D_ * 2, 256, 0, stream>>>(u, v, w1t, qterm, xg);
    k_f1  <<<64, 256, 0, stream>>>(xg, f1w, f1b, s1g);
    k_f2  <<<128, 256, 0, stream>>>(s1g, f2w, f2b, s2g);
    k_f3  <<<B_, 256, 0, stream>>>(s2g, f3w, f3b, (float*)d_out);
}

// Round 6
// 193.535 us; speedup vs baseline: 2.7626x; 1.0471x over previous
//
#include <hip/hip_runtime.h>
#include <hip/hip_bf16.h>

#define B_  8
#define D_  128
#define K_  7
#define Q_  256
#define G0_ 511
#define G0P 512
#define G1_ 512
#define F1_ 512
#define F2_ 1024
#define OUT_ 16

typedef __bf16 bf16x8 __attribute__((ext_vector_type(8)));
typedef float  f32x4  __attribute__((ext_vector_type(4)));

// async global->LDS: one instruction = 64 lanes x 16B = 1KB.
// LDS dest = wave-uniform base + lane*16B.
#define GL2LDS(g, l) __builtin_amdgcn_global_load_lds(                        \
    (const __attribute__((address_space(1))) void*)(g),                       \
    (__attribute__((address_space(3))) void*)(l), 16, 0, 0)

// ---------------------------------------------------------------------------
// k_prep: fused preprocessing, 2092 blocks x 256 threads.
//  [0,1024):      u/v rows                                  (R3-verified)
//  [1024,1280):   w1 -> swizzled bf16 w1t (R3-verified layout)
//  [1280,1312):   qterm                                     (R3-verified)
//  [1312,1320):   zero xg                                   (R3-verified)
//  [1320,1576):   f1w transpose -> f1t[o][k]
//  [1576,2088):   f2w transpose -> f2t[o][k]
//  [2088,2092):   f3w transpose -> f3t[o][k]
__global__ void k_prep(const float* __restrict__ x, const float* __restrict__ g0w,
                       const float* __restrict__ g0b, const float* __restrict__ qst,
                       const float* __restrict__ g1w, const float* __restrict__ g1b,
                       const float* __restrict__ f1w, const float* __restrict__ f2w,
                       const float* __restrict__ f3w,
                       float* __restrict__ u, float* __restrict__ v,
                       __bf16* __restrict__ w1t, float* __restrict__ qterm,
                       float* __restrict__ xg, float* __restrict__ f1t,
                       float* __restrict__ f2t, float* __restrict__ f3t) {
    const int blk = blockIdx.x;
    const int t   = threadIdx.x;
    if (blk < 1024) {
        __shared__ float xs[8];
        if (t < K_) xs[t] = x[blk * K_ + t];
        __syncthreads();
        #pragma unroll
        for (int h = 0; h < 2; ++h) {
            const int g = t + h * 256;
            float su = 0.f, sv = 0.f;
            if (g < G0_) {
                #pragma unroll
                for (int k = 0; k < K_; ++k) {
                    su += xs[k] * g0w[k * G0_ + g];
                    sv += xs[k] * g0w[(K_ + k) * G0_ + g];
                }
                su += g0b[g];
            }
            u[blk * G0P + g] = (g < G0_) ? su : 0.f;
            v[blk * G0P + g] = (g < G0_) ? sv : 0.f;
        }
    } else if (blk < 1280) {
        // R3-verified: w1t[kq*16384 + n*32 + slot*8 + j], slot = chunk^((n>>1)&3)
        __shared__ __bf16 tile[32][33];
        const int bb = blk - 1024;
        const int bx = bb & 15, by = bb >> 4;   // by = kq tile (k = by*32+c)
        const int r = t >> 5, c = t & 31;
        #pragma unroll
        for (int i = 0; i < 4; ++i) {
            const int k = by * 32 + r + i * 8;
            const int n = bx * 32 + c;
            tile[r + i * 8][c] = (__bf16)((k < G0_) ? g1w[k * G1_ + n] : 0.f);
        }
        __syncthreads();
        #pragma unroll
        for (int i = 0; i < 4; ++i) {
            const int n = bx * 32 + r + i * 8;
            const int cc = (c >> 3) & 3, j = c & 7;
            const int slot = cc ^ ((n >> 1) & 3);
            w1t[by * 16384 + n * 32 + slot * 8 + j] = tile[c][r + i * 8];
        }
    } else if (blk < 1312) {
        __shared__ float qs[256];
        __shared__ float red[2][128];
        const int qb = blk - 1280;
        const int b = qb >> 2, nb = (qb & 3) << 7;
        qs[t] = qst[b * Q_ + t];
        __syncthreads();
        const int n = nb + (t & 127);
        const int qh = (t >> 7) * 128;
        float s = 0.f;
        #pragma unroll 8
        for (int q = 0; q < 128; ++q)
            s += qs[qh + q] * g1w[(G0_ + qh + q) * G1_ + n];
        red[t >> 7][t & 127] = s;
        __syncthreads();
        if (t < 128)
            qterm[b * G1_ + nb + t] = red[0][t] + red[1][t] + g1b[nb + t];
    } else if (blk < 1320) {
        const int b = blk - 1312;
        xg[b * G1_ + t] = 0.f;
        xg[b * G1_ + 256 + t] = 0.f;
    } else if (blk < 1576) {
        __shared__ float tile[32][33];
        const int j = blk - 1320;
        const int bo = j & 15, bk = j >> 4;
        const int r = t >> 5, c = t & 31;
        #pragma unroll
        for (int i = 0; i < 4; ++i)
            tile[r + i * 8][c] = f1w[(bk * 32 + r + i * 8) * F1_ + bo * 32 + c];
        __syncthreads();
        #pragma unroll
        for (int i = 0; i < 4; ++i)
            f1t[(bo * 32 + r + i * 8) * G1_ + bk * 32 + c] = tile[c][r + i * 8];
    } else if (blk < 2088) {
        __shared__ float tile[32][33];
        const int j = blk - 1576;
        const int bo = j & 31, bk = j >> 5;
        const int r = t >> 5, c = t & 31;
        #pragma unroll
        for (int i = 0; i < 4; ++i)
            tile[r + i * 8][c] = f2w[(bk * 32 + r + i * 8) * F2_ + bo * 32 + c];
        __syncthreads();
        #pragma unroll
        for (int i = 0; i < 4; ++i)
            f2t[(bo * 32 + r + i * 8) * F1_ + bk * 32 + c] = tile[c][r + i * 8];
    } else {
        const int k = (blk - 2088) * 256 + t;
        float4 r0 = *(const float4*)(f3w + k * OUT_);
        float4 r1 = *(const float4*)(f3w + k * OUT_ + 4);
        float4 r2 = *(const float4*)(f3w + k * OUT_ + 8);
        float4 r3 = *(const float4*)(f3w + k * OUT_ + 12);
        const float rr[16] = {r0.x,r0.y,r0.z,r0.w, r1.x,r1.y,r1.z,r1.w,
                              r2.x,r2.y,r2.z,r2.w, r3.x,r3.y,r3.z,r3.w};
        #pragma unroll
        for (int o = 0; o < 16; ++o) f3t[o * F2_ + k] = rr[o];
    }
}

// ---------------------------------------------------------------------------
// k_pair: R3-VERIFIED core (16x16x32 MFMA). block = (b, a, nhalf).
// M=128, N=256, K=512. A = relu(u[c]+v_a) staged in LDS (fragment order);
// B DMA'd via global_load_lds from pre-tiled swizzled w1t; double-buffered.
__global__ __launch_bounds__(256, 2)
void k_pair(const float* __restrict__ u, const float* __restrict__ v,
            const __bf16* __restrict__ w1t, const float* __restrict__ qterm,
            float* __restrict__ xg) {
    __shared__ float  v_a[512];
    __shared__ __bf16 At[2][4096];     // [buf][mtile(8)][lane(64)*8]
    __shared__ __bf16 Bt[2][8192];     // [buf][n_local(256)][32k swizzled]
    __shared__ float  ebuf[4][128];

    const int bid  = blockIdx.x;
    const int b    = bid >> 8;
    const int a    = (bid >> 1) & 127;
    const int nbase = (bid & 1) << 8;
    const int tid  = threadIdx.x;
    const int wave = tid >> 6, lane = tid & 63;
    const int quad = lane >> 4, l15 = lane & 15;
    const int nloc = (wave >> 1) * 128;    // wave's n offset within [0,256)
    const int mtg  = (wave & 1) * 4;       // wave's mtile base
    const int swz  = (l15 >> 1) & 3;

    if (tid < 128)
        *(float4*)(v_a + tid * 4) = *(const float4*)(v + (b * D_ + a) * G0P + tid * 4);

    // B staging: wave issues 4 DMA instrs, instr j covers n_local [(wave*4+j)*16,+16)
    const int iw0 = wave * 4;
    const __bf16* gsrc = w1t + (size_t)(nbase + iw0 * 16 + (lane >> 2)) * 32
                             + (lane & 3) * 8;

    // A staging geometry: thread -> (m = tid>>1, k-off = (tid&1)*16)
    const int sm = tid >> 1;
    const int sk = (tid & 1) << 4;
    const float* urow = u + (b * D_ + sm) * G0P + sk;
    const int woff = (sm >> 4) * 512 + (sk >> 3) * 128 + (sm & 15) * 8;

    f32x4 acc[4][8];
    #pragma unroll
    for (int mt = 0; mt < 4; ++mt)
        #pragma unroll
        for (int nt = 0; nt < 8; ++nt)
            acc[mt][nt] = (f32x4){0.f, 0.f, 0.f, 0.f};

    float4 u0, u1, u2, u3;
    auto load_u = [&](int kq) {
        const float* p = urow + kq * 32;
        u0 = *(const float4*)p;       u1 = *(const float4*)(p + 4);
        u2 = *(const float4*)(p + 8); u3 = *(const float4*)(p + 12);
    };
    auto stage_B = [&](int buf, int kq) {
        const __bf16* g = gsrc + kq * 16384;
        __bf16* l = &Bt[buf][iw0 * 512];
        #pragma unroll
        for (int j = 0; j < 4; ++j)
            GL2LDS(g + j * 512, l + j * 512);
    };
    auto write_A = [&](int buf, int kq) {
        const float* vp = v_a + kq * 32 + sk;
        const float4 v0 = *(const float4*)vp,       v1 = *(const float4*)(vp + 4);
        const float4 v2 = *(const float4*)(vp + 8), v3 = *(const float4*)(vp + 12);
        bf16x8 h0, h1;
        h0[0] = (__bf16)fmaxf(u0.x + v0.x, 0.f);
        h0[1] = (__bf16)fmaxf(u0.y + v0.y, 0.f);
        h0[2] = (__bf16)fmaxf(u0.z + v0.z, 0.f);
        h0[3] = (__bf16)fmaxf(u0.w + v0.w, 0.f);
        h0[4] = (__bf16)fmaxf(u1.x + v1.x, 0.f);
        h0[5] = (__bf16)fmaxf(u1.y + v1.y, 0.f);
        h0[6] = (__bf16)fmaxf(u1.z + v1.z, 0.f);
        h0[7] = (__bf16)fmaxf(u1.w + v1.w, 0.f);
        h1[0] = (__bf16)fmaxf(u2.x + v2.x, 0.f);
        h1[1] = (__bf16)fmaxf(u2.y + v2.y, 0.f);
        h1[2] = (__bf16)fmaxf(u2.z + v2.z, 0.f);
        h1[3] = (__bf16)fmaxf(u2.w + v2.w, 0.f);
        h1[4] = (__bf16)fmaxf(u3.x + v3.x, 0.f);
        h1[5] = (__bf16)fmaxf(u3.y + v3.y, 0.f);
        h1[6] = (__bf16)fmaxf(u3.z + v3.z, 0.f);
        h1[7] = (__bf16)fmaxf(u3.w + v3.w, 0.f);
        __bf16* w = &At[buf][woff];
        *(bf16x8*)w = h0;
        *(bf16x8*)(w + 128) = h1;
    };

    // prologue
    stage_B(0, 0);
    load_u(0);
    __syncthreads();               // v_a visible, Bt[0] DMA drained
    write_A(0, 0);
    __syncthreads();               // At[0] visible

    for (int kq = 0; kq < 16; ++kq) {
        const int buf = kq & 1;
        if (kq < 15) {
            stage_B(buf ^ 1, kq + 1);      // async DMA into other buffer
            load_u(kq + 1);                // u regs for next A tile
        }
        bf16x8 af[4];
        #pragma unroll
        for (int mt = 0; mt < 4; ++mt)
            af[mt] = *(const bf16x8*)&At[buf][(mtg + mt) * 512 + lane * 8];
        bf16x8 bfr[8];
        const __bf16* btb = &Bt[buf][(nloc + l15) * 32 + ((quad ^ swz) << 3)];
        #pragma unroll
        for (int nt = 0; nt < 8; ++nt)
            bfr[nt] = *(const bf16x8*)(btb + nt * 512);
        #pragma unroll
        for (int mt = 0; mt < 4; ++mt)
            #pragma unroll
            for (int nt = 0; nt < 8; ++nt)
                acc[mt][nt] = __builtin_amdgcn_mfma_f32_16x16x32_bf16(
                    af[mt], bfr[nt], acc[mt][nt], 0, 0, 0);
        if (kq < 15) write_A(buf ^ 1, kq + 1);
        __syncthreads();           // drains DMA + ds_writes for buf^1
    }

    // epilogue: relu(C + qterm), reduce over 64 m-rows per wave, combine, atomic
    #pragma unroll
    for (int nt = 0; nt < 8; ++nt) {
        const float q = qterm[b * G1_ + nbase + nloc + nt * 16 + l15];
        float s = 0.f;
        #pragma unroll
        for (int mt = 0; mt < 4; ++mt)
            #pragma unroll
            for (int r = 0; r < 4; ++r)
                s += fmaxf(acc[mt][nt][r] + q, 0.f);
        s += __shfl_xor(s, 16, 64);
        s += __shfl_xor(s, 32, 64);
        if (quad == 0) ebuf[wave][nt * 16 + l15] = s;
    }
    __syncthreads();
    {
        const int grp = tid >> 7, nl = tid & 127;
        const float sv = ebuf[grp * 2][nl] + ebuf[grp * 2 + 1][nl];
        atomicAdd(xg + b * G1_ + nbase + grp * 128 + nl, sv);
    }
}

// ---------------------------------------------------------------------------
// f-MLP: one wave per output dot, transposed weights, coalesced float4 reads.
__global__ void k_f1(const float* __restrict__ xg, const float* __restrict__ f1t,
                     const float* __restrict__ f1b, float* __restrict__ s1g) {
    const int wave = threadIdx.x >> 6, lane = threadIdx.x & 63;
    const int id = blockIdx.x * 4 + wave;         // [0,4096)
    const int b = id >> 9, oo = id & 511;
    const float* xr = xg + b * G1_ + lane * 8;
    const float* wr = f1t + oo * G1_ + lane * 8;
    const float4 a0 = *(const float4*)xr, a1 = *(const float4*)(xr + 4);
    const float4 b0 = *(const float4*)wr, b1 = *(const float4*)(wr + 4);
    float s = a0.x*b0.x + a0.y*b0.y + a0.z*b0.z + a0.w*b0.w
            + a1.x*b1.x + a1.y*b1.y + a1.z*b1.z + a1.w*b1.w;
    #pragma unroll
    for (int off = 32; off >= 1; off >>= 1) s += __shfl_xor(s, off, 64);
    if (lane == 0) s1g[b * F1_ + oo] = fmaxf(s + f1b[oo], 0.f);
}

__global__ void k_f2(const float* __restrict__ s1g, const float* __restrict__ f2t,
                     const float* __restrict__ f2b, float* __restrict__ s2g) {
    const int wave = threadIdx.x >> 6, lane = threadIdx.x & 63;
    const int id = blockIdx.x * 4 + wave;         // [0,8192)
    const int b = id >> 10, oo = id & 1023;
    const float* xr = s1g + b * F1_ + lane * 8;
    const float* wr = f2t + oo * F1_ + lane * 8;
    const float4 a0 = *(const float4*)xr, a1 = *(const float4*)(xr + 4);
    const float4 b0 = *(const float4*)wr, b1 = *(const float4*)(wr + 4);
    float s = a0.x*b0.x + a0.y*b0.y + a0.z*b0.z + a0.w*b0.w
            + a1.x*b1.x + a1.y*b1.y + a1.z*b1.z + a1.w*b1.w;
    #pragma unroll
    for (int off = 32; off >= 1; off >>= 1) s += __shfl_xor(s, off, 64);
    if (lane == 0) s2g[b * F2_ + oo] = fmaxf(s + f2b[oo], 0.f);
}

__global__ void k_f3(const float* __restrict__ s2g, const float* __restrict__ f3t,
                     const float* __restrict__ f3b, float* __restrict__ out) {
    const int b = blockIdx.x, t = threadIdx.x;
    const int wave = t >> 6, lane = t & 63;
    __shared__ float lg[16];
    float4 xs[4];
    #pragma unroll
    for (int j = 0; j < 4; ++j)
        xs[j] = *(const float4*)(s2g + b * F2_ + lane * 16 + j * 4);
    #pragma unroll
    for (int oi = 0; oi < 4; ++oi) {
        const int o = wave * 4 + oi;
        const float* wr = f3t + o * F2_ + lane * 16;
        float s = 0.f;
        #pragma unroll
        for (int j = 0; j < 4; ++j) {
            const float4 w = *(const float4*)(wr + j * 4);
            s += xs[j].x*w.x + xs[j].y*w.y + xs[j].z*w.z + xs[j].w*w.w;
        }
        #pragma unroll
        for (int off = 32; off >= 1; off >>= 1) s += __shfl_xor(s, off, 64);
        if (lane == 0) lg[o] = s + f3b[o];
    }
    __syncthreads();
    if (t < 16) {
        float m = -1e30f;
        #pragma unroll
        for (int i = 0; i < 16; ++i) m = fmaxf(m, lg[i]);
        float se = 0.f;
        #pragma unroll
        for (int i = 0; i < 16; ++i) se += __expf(lg[i] - m);
        out[b * OUT_ + t] = lg[t] - m - logf(se);
    }
}

// ---------------------------------------------------------------------------
extern "C" void kernel_launch(void* const* d_in, const int* in_sizes, int n_in,
                              void* d_out, int out_size, void* d_ws, size_t ws_size,
                              hipStream_t stream) {
    const float* x   = (const float*)d_in[0];
    const float* qst = (const float*)d_in[1];
    const float* g0w = (const float*)d_in[2];
    const float* g0b = (const float*)d_in[3];
    const float* g1w = (const float*)d_in[4];
    const float* g1b = (const float*)d_in[5];
    const float* f1w = (const float*)d_in[6];
    const float* f1b = (const float*)d_in[7];
    const float* f2w = (const float*)d_in[8];
    const float* f2b = (const float*)d_in[9];
    const float* f3w = (const float*)d_in[10];
    const float* f3b = (const float*)d_in[11];

    char* ws = (char*)d_ws;
    float*  u     = (float*)ws;  ws += (size_t)B_ * D_ * G0P * 4;   // 2 MB
    float*  v     = (float*)ws;  ws += (size_t)B_ * D_ * G0P * 4;   // 2 MB
    __bf16* w1t   = (__bf16*)ws; ws += (size_t)G1_ * G0P * 2;       // 512 KB
    float*  qterm = (float*)ws;  ws += (size_t)B_ * G1_ * 4;
    float*  xg    = (float*)ws;  ws += (size_t)B_ * G1_ * 4;
    float*  s1g   = (float*)ws;  ws += (size_t)B_ * F1_ * 4;
    float*  s2g   = (float*)ws;  ws += (size_t)B_ * F2_ * 4;
    float*  f1t   = (float*)ws;  ws += (size_t)F1_ * G1_ * 4;       // 1 MB
    float*  f2t   = (float*)ws;  ws += (size_t)F2_ * F1_ * 4;       // 2 MB
    float*  f3t   = (float*)ws;  ws += (size_t)OUT_ * F2_ * 4;      // 64 KB

    k_prep<<<2092, 256, 0, stream>>>(x, g0w, g0b, qst, g1w, g1b, f1w, f2w, f3w,
                                     u, v, w1t, qterm, xg, f1t, f2t, f3t);
    k_pair<<<B_ * D_ * 2, 256, 0, stream>>>(u, v, w1t, qterm, xg);
    k_f1  <<<1024, 256, 0, stream>>>(xg, f1t, f1b, s1g);
    k_f2  <<<2048, 256, 0, stream>>>(s1g, f2t, f2b, s2g);
    k_f3  <<<B_, 256, 0, stream>>>(s2g, f3t, f3b, (float*)d_out);
}